// Round 2
// baseline (915.135 us; speedup 1.0000x reference)
//
#include <hip/hip_runtime.h>

#define BB 32
#define NN 576
#define DD 1024
#define KK 128
#define HS_N 577

// ---------------- norm kernel: inv[b,n] = 1/||feats[b,n,:]|| ----------------
__global__ __launch_bounds__(256) void norm_kernel(const float* __restrict__ hs,
                                                   float* __restrict__ inv) {
    int row = blockIdx.x;              // b*NN + n
    int b = row / NN, n = row % NN;
    const float4* p = (const float4*)(hs + ((size_t)b * HS_N + n + 1) * DD);
    int t = threadIdx.x;
    float4 v = p[t];
    double s = (double)v.x * v.x + (double)v.y * v.y + (double)v.z * v.z + (double)v.w * v.w;
    for (int off = 32; off; off >>= 1) s += __shfl_xor(s, off);
    __shared__ double wsum[4];
    int lane = t & 63, w = t >> 6;
    if (lane == 0) wsum[w] = s;
    __syncthreads();
    if (t == 0) {
        double tot = wsum[0] + wsum[1] + wsum[2] + wsum[3];
        inv[row] = 1.0f / (float)sqrt(tot);
    }
}

// ---------------- sim GEMM (symmetric): only 45 upper-tri 64x64 tile pairs --
#define KC 16
#define LDT 68   // padded LDS stride
#define TLD 68   // transpose-bounce stride
__global__ __launch_bounds__(256) void sim_kernel(const float* __restrict__ hs,
                                                  const float* __restrict__ inv,
                                                  float* __restrict__ sim) {
    int b = blockIdx.z;
    int l = blockIdx.x;                // 0..44 -> (ti,tj), ti<=tj
    int ti = 0;
    while (l >= 9 - ti) { l -= 9 - ti; ti++; }
    int tj = ti + l;
    int m0 = ti * 64, n0 = tj * 64;
    const float* feats = hs + ((size_t)b * HS_N + 1) * DD;
    __shared__ float As[KC * LDT];
    __shared__ float Bs[KC * LDT];
    __shared__ float tile[64 * TLD];
    int t = threadIdx.x;
    int lrow = t >> 2, lc4 = (t & 3) << 2;     // 64 rows x 4 float4-cols
    float invA = inv[b * NN + m0 + lrow];
    float invB = inv[b * NN + n0 + lrow];
    const float* gA = feats + (size_t)(m0 + lrow) * DD + lc4;
    const float* gB = feats + (size_t)(n0 + lrow) * DD + lc4;
    int tx = t & 15, ty = t >> 4;
    float acc[4][4] = {};
    for (int k0 = 0; k0 < DD; k0 += KC) {
        float4 a = *(const float4*)(gA + k0);
        float4 bv = *(const float4*)(gB + k0);
        __syncthreads();
        // store transposed [k][m], scaled at load (matches reference normalize-then-dot)
        As[(lc4 + 0) * LDT + lrow] = a.x * invA;
        As[(lc4 + 1) * LDT + lrow] = a.y * invA;
        As[(lc4 + 2) * LDT + lrow] = a.z * invA;
        As[(lc4 + 3) * LDT + lrow] = a.w * invA;
        Bs[(lc4 + 0) * LDT + lrow] = bv.x * invB;
        Bs[(lc4 + 1) * LDT + lrow] = bv.y * invB;
        Bs[(lc4 + 2) * LDT + lrow] = bv.z * invB;
        Bs[(lc4 + 3) * LDT + lrow] = bv.w * invB;
        __syncthreads();
#pragma unroll
        for (int kk = 0; kk < KC; kk++) {
            float4 av = *(const float4*)&As[kk * LDT + (tx << 2)];
            float4 bw = *(const float4*)&Bs[kk * LDT + (ty << 2)];
            float aa[4] = {av.x, av.y, av.z, av.w};
            float bb[4] = {bw.x, bw.y, bw.z, bw.w};
#pragma unroll
            for (int i = 0; i < 4; i++)
#pragma unroll
                for (int j = 0; j < 4; j++) acc[i][j] += aa[i] * bb[j];
        }
    }
    // normal-orientation tile write (coalesced float4)
#pragma unroll
    for (int i = 0; i < 4; i++) {
        size_t m = m0 + (tx << 2) + i;
        float4 o = {acc[i][0], acc[i][1], acc[i][2], acc[i][3]};
        *(float4*)(sim + ((size_t)b * NN + m) * NN + n0 + (ty << 2)) = o;
    }
    if (ti != tj) {
        // mirror tile via LDS bounce; same float values -> bitwise symmetric
        __syncthreads();
#pragma unroll
        for (int i = 0; i < 4; i++) {
            float4 o = {acc[i][0], acc[i][1], acc[i][2], acc[i][3]};
            *(float4*)&tile[((tx << 2) + i) * TLD + (ty << 2)] = o;
        }
        __syncthreads();
#pragma unroll
        for (int r = 0; r < 4; r++) {
            int a = (tx << 2) + r;                 // local n index (output row)
            float4 o;
            o.x = tile[((ty << 2) + 0) * TLD + a];
            o.y = tile[((ty << 2) + 1) * TLD + a];
            o.z = tile[((ty << 2) + 2) * TLD + a];
            o.w = tile[((ty << 2) + 3) * TLD + a];
            *(float4*)(sim + ((size_t)b * NN + n0 + a) * NN + m0 + (ty << 2)) = o;
        }
    }
}

// -------- init gains on all CUs: g0[b,m] = sum_n max(sim[b,m,n],0) ----------
// Also zeroes the 576-float pad row after sim (dummy-column reads for b=31
// land there; b<31 dummy reads hit batch b+1's sim -- finite either way, and
// d == 0 exactly for the dummy column since its ovnw has o == nw == 0).
__global__ __launch_bounds__(256) void init_gain_kernel(const float* __restrict__ sim,
                                                        double* __restrict__ g0,
                                                        float* __restrict__ pad) {
    if (blockIdx.x == 0 && blockIdx.y == 0) {
        int tt = threadIdx.x;
        pad[tt] = 0.f; pad[tt + 256] = 0.f;
        if (tt < 64) pad[tt + 512] = 0.f;
    }
    int b = blockIdx.y;
    int m = (blockIdx.x << 2) + (threadIdx.x >> 6);
    int lane = threadIdx.x & 63;
    const float* row = sim + ((size_t)b * NN + m) * NN;
    double s = 0.0;
#pragma unroll
    for (int j = 0; j < 9; j++) s += (double)fmaxf(row[(j << 6) + lane], 0.f);
    for (int off = 32; off; off >>= 1) s += __shfl_xor(s, off);
    if (lane == 0) g0[b * NN + m] = s;
}

// ------- selection: 3 waves x 3 candidates, 2 light barriers/step -----------
// Layout = round-0 best (192 threads, ILP-16x3, 48 loads in flight,
// launch_bounds(192,1) for the 256-VGPR budget). Phase-1 inner math upgraded
// with the round-1-VALIDATED med3 identity (absmax 0.0 on that path):
//     max(x-nw,0) - max(x-o,0)  ==  o - med3(x, o, nw)      (o <= nw)
// i.e. fminf(fmaxf(x,o),nw) -> v_med3_f32, one f32 sub, one cvt, one f64 add
// (~10 cy/pair vs ~26 before). No per-pair validity cndmask: chlist is padded
// to a multiple of 16 with dummy column NN whose ovnw = (0,0) -> d == 0
// exactly. No wave vote (round 1 showed it costs more than it saves at the
// large-cc steps that dominate).
__global__ __launch_bounds__(192, 1) void select_kernel(const float* __restrict__ sim,
                                                        const double* __restrict__ g0,
                                                        const float* __restrict__ cls,
                                                        float* __restrict__ out_idx,
                                                        int* __restrict__ gsorted) {
    int b = blockIdx.x;
    const float* S = sim + (size_t)b * NN * NN;
    int t = threadIdx.x, lane = t & 63, w = t >> 6;   // w in 0..2
    __shared__ float2 ovnw[NN + 1];        // (old cmax, new cmax); slot NN = dummy
    __shared__ int    chlist[NN + 16];
    __shared__ unsigned long long chmask[9];
    __shared__ double rv[3];
    __shared__ int    ri[3];
    __shared__ float  selseq[KK];
    __shared__ int    wcnt9[9];

    double gg[3], cl[3];
    float mycmax[3] = {0.f, 0.f, 0.f};
    bool sel[3] = {false, false, false};
#pragma unroll
    for (int u = 0; u < 3; u++) {
        cl[u] = (double)cls[b * NN + t + 192 * u];
        gg[u] = g0[b * NN + t + 192 * u];
    }
    if (t == 0) ovnw[NN] = make_float2(0.f, 0.f);
    const int c0 = t, c1 = t + 192, c2 = t + 384;

    for (int k = 0; k < KK; k++) {
        // ---- phase 1: delta-update over step-(k-1) changed columns ----
        if (k > 0) {
            int pos = 0;
#pragma unroll
            for (int q = 0; q < 9; q++) {
                unsigned long long m = chmask[q];
                if ((m >> lane) & 1ull)
                    chlist[pos + __popcll(m & ((1ull << lane) - 1ull))] = (q << 6) + lane;
                pos += __popcll(m);
            }
            int cc = pos;
            int padc = (16 - (cc & 15)) & 15;
            if (lane < padc) chlist[cc + lane] = NN;   // dummy col: d == 0 exactly
            int ccr = cc + padc;
            for (int j = 0; j < ccr; j += 16) {
                int nq[16]; float x0[16], x1[16], x2[16]; float2 on[16];
#pragma unroll
                for (int q = 0; q < 16; q++) nq[q] = chlist[j + q];   // wave-uniform
#pragma unroll
                for (int q = 0; q < 16; q++) {
                    const float* rp = S + (size_t)nq[q] * NN + t;
                    x0[q] = rp[0]; x1[q] = rp[192]; x2[q] = rp[384];
                }
#pragma unroll
                for (int q = 0; q < 16; q++) on[q] = ovnw[nq[q]];  // broadcast
#pragma unroll
                for (int q = 0; q < 16; q++) {
                    float o = on[q].x, nw = on[q].y;
                    gg[0] += (double)(o - fminf(fmaxf(x0[q], o), nw));
                    gg[1] += (double)(o - fminf(fmaxf(x1[q], o), nw));
                    gg[2] += (double)(o - fminf(fmaxf(x2[q], o), nw));
                }
            }
        }
        // ---- argmax: local 3-way (strict > keeps smaller c on ties) ----
        double v = sel[0] ? -1.0 : gg[0] * cl[0];
        int idx = c0;
        {
            double v1 = sel[1] ? -1.0 : gg[1] * cl[1];
            if (v1 > v) { v = v1; idx = c1; }
            double v2 = sel[2] ? -1.0 : gg[2] * cl[2];
            if (v2 > v) { v = v2; idx = c2; }
        }
        for (int off = 32; off; off >>= 1) {
            double ov = __shfl_xor(v, off);
            int oi = __shfl_xor(idx, off);
            if (ov > v || (ov == v && oi < idx)) { v = ov; idx = oi; }
        }
        if (lane == 0) { rv[w] = v; ri[w] = idx; }
        __syncthreads();                           // A
        double bv = rv[0]; int mstar = ri[0];
        { double qv = rv[1]; int qi = ri[1]; if (qv > bv || (qv == bv && qi < mstar)) { bv = qv; mstar = qi; } }
        { double qv = rv[2]; int qi = ri[2]; if (qv > bv || (qv == bv && qi < mstar)) { bv = qv; mstar = qi; } }
        // ---- tail: 3 coalesced row loads, cmax update, ballots ----
        const float* rowm = S + (size_t)mstar * NN + t;
        float s0 = rowm[0], s1 = rowm[192], s2 = rowm[384];
        float o0 = mycmax[0], n0 = fmaxf(o0, s0); bool h0 = n0 > o0;
        float o1 = mycmax[1], n1 = fmaxf(o1, s1); bool h1 = n1 > o1;
        float o2 = mycmax[2], n2 = fmaxf(o2, s2); bool h2 = n2 > o2;
        unsigned long long m0 = __ballot(h0);
        unsigned long long m1 = __ballot(h1);
        unsigned long long m2 = __ballot(h2);
        ovnw[c0] = make_float2(o0, n0); mycmax[0] = n0;
        ovnw[c1] = make_float2(o1, n1); mycmax[1] = n1;
        ovnw[c2] = make_float2(o2, n2); mycmax[2] = n2;
        if (lane == 0) { chmask[w] = m0; chmask[3 + w] = m1; chmask[6 + w] = m2; }
        if (c0 == mstar) { sel[0] = true; selseq[k] = (float)(mstar + 1); }
        if (c1 == mstar) { sel[1] = true; selseq[k] = (float)(mstar + 1); }
        if (c2 == mstar) { sel[2] = true; selseq[k] = (float)(mstar + 1); }
        __syncthreads();                           // B
    }

    // ---- epilogue: write selection order + sorted gather list ----
    if (t < KK) out_idx[b * KK + t] = selseq[t];
    unsigned long long mk0 = __ballot(sel[0]);
    unsigned long long mk1 = __ballot(sel[1]);
    unsigned long long mk2 = __ballot(sel[2]);
    if (lane == 0) {
        wcnt9[w] = __popcll(mk0);
        wcnt9[3 + w] = __popcll(mk1);
        wcnt9[6 + w] = __popcll(mk2);
    }
    __syncthreads();
    int r0 = __popcll(mk0 & ((1ull << lane) - 1));
    int r1 = __popcll(mk1 & ((1ull << lane) - 1));
    int r2 = __popcll(mk2 & ((1ull << lane) - 1));
    int pre0 = 0, pre1 = 0, pre2 = 0;
#pragma unroll
    for (int q = 0; q < 9; q++) {
        int c = wcnt9[q];
        if (q < 0 + w) pre0 += c;
        if (q < 3 + w) pre1 += c;
        if (q < 6 + w) pre2 += c;
    }
    if (sel[0]) gsorted[b * KK + pre0 + r0] = c0 + 1;
    if (sel[1]) gsorted[b * KK + pre1 + r1] = c1 + 1;
    if (sel[2]) gsorted[b * KK + pre2 + r2] = c2 + 1;
}

// ---------------- gather: dominant_tokens[b,j,:] = hs[b, gsorted, :] --------
__global__ __launch_bounds__(256) void gather_kernel(const float* __restrict__ hs,
                                                     const int* __restrict__ gsorted,
                                                     float* __restrict__ out) {
    int blk = blockIdx.x;
    int b = blk >> 7, j = blk & 127;
    int row = gsorted[b * KK + j];
    const float4* src = (const float4*)(hs + ((size_t)b * HS_N + row) * DD);
    float4* dst = (float4*)(out + ((size_t)b * KK + j) * DD);
    dst[threadIdx.x] = src[threadIdx.x];
}

extern "C" void kernel_launch(void* const* d_in, const int* in_sizes, int n_in,
                              void* d_out, int out_size, void* d_ws, size_t ws_size,
                              hipStream_t stream) {
    const float* hs = (const float*)d_in[0];
    const float* cls = (const float*)d_in[1];
    // workspace layout: sim (42.5MB) | pad (576 floats, zeroed -- dummy-column
    // landing zone for b=31) | X: inv (norm->sim) / g0 (init->select, lifetimes
    // disjoint, g0 overlays inv) | gsorted (16KB)
    float* sim = (float*)d_ws;
    float* pad = sim + (size_t)BB * NN * NN;
    char* xregion = (char*)(pad + NN);
    float* inv = (float*)xregion;                  // BB*NN floats
    double* g0 = (double*)xregion;                 // BB*NN doubles (overlay)
    int* gsorted = (int*)(xregion + (size_t)BB * NN * sizeof(double));
    float* out_tokens = (float*)d_out;                       // [B,K,D] fp32
    float* out_idx = out_tokens + (size_t)BB * KK * DD;      // [B,K] indices as fp32

    norm_kernel<<<BB * NN, 256, 0, stream>>>(hs, inv);
    sim_kernel<<<dim3(45, 1, BB), 256, 0, stream>>>(hs, inv, sim);
    init_gain_kernel<<<dim3(NN / 4, BB), 256, 0, stream>>>(sim, g0, pad);
    select_kernel<<<BB, 192, 0, stream>>>(sim, g0, cls, out_idx, gsorted);
    gather_kernel<<<BB * KK, 256, 0, stream>>>(hs, gsorted, out_tokens);
}

// Round 4
// 770.849 us; speedup vs baseline: 1.1872x; 1.1872x over previous
//
#include <hip/hip_runtime.h>

#define BB 32
#define NN 576
#define DD 1024
#define KK 128
#define HS_N 577

// ---------------- norm kernel: inv[b,n] = 1/||feats[b,n,:]|| ----------------
__global__ __launch_bounds__(256) void norm_kernel(const float* __restrict__ hs,
                                                   float* __restrict__ inv) {
    int row = blockIdx.x;              // b*NN + n
    int b = row / NN, n = row % NN;
    const float4* p = (const float4*)(hs + ((size_t)b * HS_N + n + 1) * DD);
    int t = threadIdx.x;
    float4 v = p[t];
    double s = (double)v.x * v.x + (double)v.y * v.y + (double)v.z * v.z + (double)v.w * v.w;
    for (int off = 32; off; off >>= 1) s += __shfl_xor(s, off);
    __shared__ double wsum[4];
    int lane = t & 63, w = t >> 6;
    if (lane == 0) wsum[w] = s;
    __syncthreads();
    if (t == 0) {
        double tot = wsum[0] + wsum[1] + wsum[2] + wsum[3];
        inv[row] = 1.0f / (float)sqrt(tot);
    }
}

// ---------------- sim GEMM (symmetric): only 45 upper-tri 64x64 tile pairs --
#define KC 16
#define LDT 68   // padded LDS stride
#define TLD 68   // transpose-bounce stride
__global__ __launch_bounds__(256) void sim_kernel(const float* __restrict__ hs,
                                                  const float* __restrict__ inv,
                                                  float* __restrict__ sim) {
    int b = blockIdx.z;
    int l = blockIdx.x;                // 0..44 -> (ti,tj), ti<=tj
    int ti = 0;
    while (l >= 9 - ti) { l -= 9 - ti; ti++; }
    int tj = ti + l;
    int m0 = ti * 64, n0 = tj * 64;
    const float* feats = hs + ((size_t)b * HS_N + 1) * DD;
    __shared__ float As[KC * LDT];
    __shared__ float Bs[KC * LDT];
    __shared__ float tile[64 * TLD];
    int t = threadIdx.x;
    int lrow = t >> 2, lc4 = (t & 3) << 2;     // 64 rows x 4 float4-cols
    float invA = inv[b * NN + m0 + lrow];
    float invB = inv[b * NN + n0 + lrow];
    const float* gA = feats + (size_t)(m0 + lrow) * DD + lc4;
    const float* gB = feats + (size_t)(n0 + lrow) * DD + lc4;
    int tx = t & 15, ty = t >> 4;
    float acc[4][4] = {};
    for (int k0 = 0; k0 < DD; k0 += KC) {
        float4 a = *(const float4*)(gA + k0);
        float4 bv = *(const float4*)(gB + k0);
        __syncthreads();
        // store transposed [k][m], scaled at load (matches reference normalize-then-dot)
        As[(lc4 + 0) * LDT + lrow] = a.x * invA;
        As[(lc4 + 1) * LDT + lrow] = a.y * invA;
        As[(lc4 + 2) * LDT + lrow] = a.z * invA;
        As[(lc4 + 3) * LDT + lrow] = a.w * invA;
        Bs[(lc4 + 0) * LDT + lrow] = bv.x * invB;
        Bs[(lc4 + 1) * LDT + lrow] = bv.y * invB;
        Bs[(lc4 + 2) * LDT + lrow] = bv.z * invB;
        Bs[(lc4 + 3) * LDT + lrow] = bv.w * invB;
        __syncthreads();
#pragma unroll
        for (int kk = 0; kk < KC; kk++) {
            float4 av = *(const float4*)&As[kk * LDT + (tx << 2)];
            float4 bw = *(const float4*)&Bs[kk * LDT + (ty << 2)];
            float aa[4] = {av.x, av.y, av.z, av.w};
            float bb[4] = {bw.x, bw.y, bw.z, bw.w};
#pragma unroll
            for (int i = 0; i < 4; i++)
#pragma unroll
                for (int j = 0; j < 4; j++) acc[i][j] += aa[i] * bb[j];
        }
    }
    // normal-orientation tile write (coalesced float4)
#pragma unroll
    for (int i = 0; i < 4; i++) {
        size_t m = m0 + (tx << 2) + i;
        float4 o = {acc[i][0], acc[i][1], acc[i][2], acc[i][3]};
        *(float4*)(sim + ((size_t)b * NN + m) * NN + n0 + (ty << 2)) = o;
    }
    if (ti != tj) {
        // mirror tile via LDS bounce; same float values -> bitwise symmetric
        __syncthreads();
#pragma unroll
        for (int i = 0; i < 4; i++) {
            float4 o = {acc[i][0], acc[i][1], acc[i][2], acc[i][3]};
            *(float4*)&tile[((tx << 2) + i) * TLD + (ty << 2)] = o;
        }
        __syncthreads();
#pragma unroll
        for (int r = 0; r < 4; r++) {
            int a = (tx << 2) + r;                 // local n index (output row)
            float4 o;
            o.x = tile[((ty << 2) + 0) * TLD + a];
            o.y = tile[((ty << 2) + 1) * TLD + a];
            o.z = tile[((ty << 2) + 2) * TLD + a];
            o.w = tile[((ty << 2) + 3) * TLD + a];
            *(float4*)(sim + ((size_t)b * NN + n0 + a) * NN + m0 + (ty << 2)) = o;
        }
    }
}

// -------- init gains on all CUs: g0[b,m] = sum_n max(sim[b,m,n],0) ----------
// Also zeroes the 576-float pad row after sim (dummy-column reads for b=31
// land there; b<31 dummy reads hit batch b+1's sim -- finite either way, and
// d == 0 exactly for the dummy column since its ovnw has o == nw == 0).
__global__ __launch_bounds__(256) void init_gain_kernel(const float* __restrict__ sim,
                                                        double* __restrict__ g0,
                                                        float* __restrict__ pad) {
    if (blockIdx.x == 0 && blockIdx.y == 0) {
        int tt = threadIdx.x;
        pad[tt] = 0.f; pad[tt + 256] = 0.f;
        if (tt < 64) pad[tt + 512] = 0.f;
    }
    int b = blockIdx.y;
    int m = (blockIdx.x << 2) + (threadIdx.x >> 6);
    int lane = threadIdx.x & 63;
    const float* row = sim + ((size_t)b * NN + m) * NN;
    double s = 0.0;
#pragma unroll
    for (int j = 0; j < 9; j++) s += (double)fmaxf(row[(j << 6) + lane], 0.f);
    for (int off = 32; off; off >>= 1) s += __shfl_xor(s, off);
    if (lane == 0) g0[b * NN + m] = s;
}

// ------- selection: 3 waves x 3 candidates, 2 light barriers/step -----------
// v3 (resubmit -- round-3 bench died on container acquisition, no data):
// round-2 post-mortem showed the loop is LOAD-LATENCY bound: med3 cut VALU
// work 35% but time went UP because the register allocator (VGPR 100 -> 60)
// collapsed the 48-load batch into small load/compute clusters, killing MLP.
// Fix: EXPLICIT double-buffered software pipeline -- issue batch j+1's 48
// loads (named B regs) before computing batch j (named A regs), pinned with
// sched_barrier(0) so the compiler cannot re-fuse the regions. 1 wave/SIMD
// (launch_bounds(192,1)) leaves ~450 VGPRs: both buffers (2 x ~96 regs) stay
// register-resident. Arithmetic identical in identical order to round 2
// (absmax 0.0 validated): med3 identity
//     max(x-nw,0) - max(x-o,0)  ==  o - med3(x, o, nw)      (o <= nw)
// and dummy-column padding (chlist padded to x16 with col NN, ovnw[NN]=(0,0)
// -> d == 0 exactly). The tail prefetch (jn clamped) issues redundant loads
// that feed no compute -- exactness preserved.
#define LOAD_BUF(NQ, X0, X1, X2, ON, J)                                        \
    {                                                                          \
        int jj16 = (J) << 4;                                                   \
        _Pragma("unroll") for (int q = 0; q < 16; q++)                         \
            NQ[q] = chlist[jj16 + q]; /* wave-uniform */                       \
        _Pragma("unroll") for (int q = 0; q < 16; q++) {                       \
            const float* rp = S + (size_t)NQ[q] * NN + t;                      \
            X0[q] = rp[0]; X1[q] = rp[192]; X2[q] = rp[384];                   \
        }                                                                      \
        _Pragma("unroll") for (int q = 0; q < 16; q++) ON[q] = ovnw[NQ[q]];    \
    }

#define COMP_BUF(X0, X1, X2, ON)                                               \
    {                                                                          \
        _Pragma("unroll") for (int q = 0; q < 16; q++) {                       \
            float o = ON[q].x, nw = ON[q].y;                                   \
            gg[0] += (double)(o - fminf(fmaxf(X0[q], o), nw));                 \
            gg[1] += (double)(o - fminf(fmaxf(X1[q], o), nw));                 \
            gg[2] += (double)(o - fminf(fmaxf(X2[q], o), nw));                 \
        }                                                                      \
    }

__global__ __launch_bounds__(192, 1) void select_kernel(const float* __restrict__ sim,
                                                        const double* __restrict__ g0,
                                                        const float* __restrict__ cls,
                                                        float* __restrict__ out_idx,
                                                        int* __restrict__ gsorted) {
    int b = blockIdx.x;
    const float* S = sim + (size_t)b * NN * NN;
    int t = threadIdx.x, lane = t & 63, w = t >> 6;   // w in 0..2
    __shared__ float2 ovnw[NN + 1];        // (old cmax, new cmax); slot NN = dummy
    __shared__ int    chlist[NN + 16];
    __shared__ unsigned long long chmask[9];
    __shared__ double rv[3];
    __shared__ int    ri[3];
    __shared__ float  selseq[KK];
    __shared__ int    wcnt9[9];

    double gg[3], cl[3];
    float mycmax[3] = {0.f, 0.f, 0.f};
    bool sel[3] = {false, false, false};
#pragma unroll
    for (int u = 0; u < 3; u++) {
        cl[u] = (double)cls[b * NN + t + 192 * u];
        gg[u] = g0[b * NN + t + 192 * u];
    }
    if (t == 0) ovnw[NN] = make_float2(0.f, 0.f);
    const int c0 = t, c1 = t + 192, c2 = t + 384;

    for (int k = 0; k < KK; k++) {
        // ---- phase 1: delta-update over step-(k-1) changed columns ----
        if (k > 0) {
            int pos = 0;
#pragma unroll
            for (int q = 0; q < 9; q++) {
                unsigned long long m = chmask[q];
                if ((m >> lane) & 1ull)
                    chlist[pos + __popcll(m & ((1ull << lane) - 1ull))] = (q << 6) + lane;
                pos += __popcll(m);
            }
            int cc = pos;
            int padc = (16 - (cc & 15)) & 15;
            if (lane < padc) chlist[cc + lane] = NN;   // dummy col: d == 0 exactly
            int nbat = (cc + padc) >> 4;               // >= 1 (winner's row always changes)

            int nqA[16]; float xA0[16], xA1[16], xA2[16]; float2 onA[16];
            int nqB[16]; float xB0[16], xB1[16], xB2[16]; float2 onB[16];
            LOAD_BUF(nqA, xA0, xA1, xA2, onA, 0);
            for (int j = 0; j < nbat; ) {
                int jn = (j + 1 < nbat) ? j + 1 : j;   // clamped prefetch (redundant, exact)
                LOAD_BUF(nqB, xB0, xB1, xB2, onB, jn);
                __builtin_amdgcn_sched_barrier(0);
                COMP_BUF(xA0, xA1, xA2, onA);
                j++;
                if (j >= nbat) break;
                jn = (j + 1 < nbat) ? j + 1 : j;
                LOAD_BUF(nqA, xA0, xA1, xA2, onA, jn);
                __builtin_amdgcn_sched_barrier(0);
                COMP_BUF(xB0, xB1, xB2, onB);
                j++;
            }
        }
        // ---- argmax: local 3-way (strict > keeps smaller c on ties) ----
        double v = sel[0] ? -1.0 : gg[0] * cl[0];
        int idx = c0;
        {
            double v1 = sel[1] ? -1.0 : gg[1] * cl[1];
            if (v1 > v) { v = v1; idx = c1; }
            double v2 = sel[2] ? -1.0 : gg[2] * cl[2];
            if (v2 > v) { v = v2; idx = c2; }
        }
        for (int off = 32; off; off >>= 1) {
            double ov = __shfl_xor(v, off);
            int oi = __shfl_xor(idx, off);
            if (ov > v || (ov == v && oi < idx)) { v = ov; idx = oi; }
        }
        if (lane == 0) { rv[w] = v; ri[w] = idx; }
        __syncthreads();                           // A
        double bv = rv[0]; int mstar = ri[0];
        { double qv = rv[1]; int qi = ri[1]; if (qv > bv || (qv == bv && qi < mstar)) { bv = qv; mstar = qi; } }
        { double qv = rv[2]; int qi = ri[2]; if (qv > bv || (qv == bv && qi < mstar)) { bv = qv; mstar = qi; } }
        // ---- tail: 3 coalesced row loads, cmax update, ballots ----
        const float* rowm = S + (size_t)mstar * NN + t;
        float s0 = rowm[0], s1 = rowm[192], s2 = rowm[384];
        float o0 = mycmax[0], n0 = fmaxf(o0, s0); bool h0 = n0 > o0;
        float o1 = mycmax[1], n1 = fmaxf(o1, s1); bool h1 = n1 > o1;
        float o2 = mycmax[2], n2 = fmaxf(o2, s2); bool h2 = n2 > o2;
        unsigned long long m0 = __ballot(h0);
        unsigned long long m1 = __ballot(h1);
        unsigned long long m2 = __ballot(h2);
        ovnw[c0] = make_float2(o0, n0); mycmax[0] = n0;
        ovnw[c1] = make_float2(o1, n1); mycmax[1] = n1;
        ovnw[c2] = make_float2(o2, n2); mycmax[2] = n2;
        if (lane == 0) { chmask[w] = m0; chmask[3 + w] = m1; chmask[6 + w] = m2; }
        if (c0 == mstar) { sel[0] = true; selseq[k] = (float)(mstar + 1); }
        if (c1 == mstar) { sel[1] = true; selseq[k] = (float)(mstar + 1); }
        if (c2 == mstar) { sel[2] = true; selseq[k] = (float)(mstar + 1); }
        __syncthreads();                           // B
    }

    // ---- epilogue: write selection order + sorted gather list ----
    if (t < KK) out_idx[b * KK + t] = selseq[t];
    unsigned long long mk0 = __ballot(sel[0]);
    unsigned long long mk1 = __ballot(sel[1]);
    unsigned long long mk2 = __ballot(sel[2]);
    if (lane == 0) {
        wcnt9[w] = __popcll(mk0);
        wcnt9[3 + w] = __popcll(mk1);
        wcnt9[6 + w] = __popcll(mk2);
    }
    __syncthreads();
    int r0 = __popcll(mk0 & ((1ull << lane) - 1));
    int r1 = __popcll(mk1 & ((1ull << lane) - 1));
    int r2 = __popcll(mk2 & ((1ull << lane) - 1));
    int pre0 = 0, pre1 = 0, pre2 = 0;
#pragma unroll
    for (int q = 0; q < 9; q++) {
        int c = wcnt9[q];
        if (q < 0 + w) pre0 += c;
        if (q < 3 + w) pre1 += c;
        if (q < 6 + w) pre2 += c;
    }
    if (sel[0]) gsorted[b * KK + pre0 + r0] = c0 + 1;
    if (sel[1]) gsorted[b * KK + pre1 + r1] = c1 + 1;
    if (sel[2]) gsorted[b * KK + pre2 + r2] = c2 + 1;
}

// ---------------- gather: dominant_tokens[b,j,:] = hs[b, gsorted, :] --------
__global__ __launch_bounds__(256) void gather_kernel(const float* __restrict__ hs,
                                                     const int* __restrict__ gsorted,
                                                     float* __restrict__ out) {
    int blk = blockIdx.x;
    int b = blk >> 7, j = blk & 127;
    int row = gsorted[b * KK + j];
    const float4* src = (const float4*)(hs + ((size_t)b * HS_N + row) * DD);
    float4* dst = (float4*)(out + ((size_t)b * KK + j) * DD);
    dst[threadIdx.x] = src[threadIdx.x];
}

extern "C" void kernel_launch(void* const* d_in, const int* in_sizes, int n_in,
                              void* d_out, int out_size, void* d_ws, size_t ws_size,
                              hipStream_t stream) {
    const float* hs = (const float*)d_in[0];
    const float* cls = (const float*)d_in[1];
    // workspace layout: sim (42.5MB) | pad (576 floats, zeroed -- dummy-column
    // landing zone for b=31) | X: inv (norm->sim) / g0 (init->select, lifetimes
    // disjoint, g0 overlays inv) | gsorted (16KB)
    float* sim = (float*)d_ws;
    float* pad = sim + (size_t)BB * NN * NN;
    char* xregion = (char*)(pad + NN);
    float* inv = (float*)xregion;                  // BB*NN floats
    double* g0 = (double*)xregion;                 // BB*NN doubles (overlay)
    int* gsorted = (int*)(xregion + (size_t)BB * NN * sizeof(double));
    float* out_tokens = (float*)d_out;                       // [B,K,D] fp32
    float* out_idx = out_tokens + (size_t)BB * KK * DD;      // [B,K] indices as fp32

    norm_kernel<<<BB * NN, 256, 0, stream>>>(hs, inv);
    sim_kernel<<<dim3(45, 1, BB), 256, 0, stream>>>(hs, inv, sim);
    init_gain_kernel<<<dim3(NN / 4, BB), 256, 0, stream>>>(sim, g0, pad);
    select_kernel<<<BB, 192, 0, stream>>>(sim, g0, cls, out_idx, gsorted);
    gather_kernel<<<BB * KK, 256, 0, stream>>>(hs, gsorted, out_tokens);
}